// Round 1
// baseline (599.805 us; speedup 1.0000x reference)
//
#include <hip/hip_runtime.h>
#include <hip/hip_bf16.h>

// ---------------- problem constants (derived at launch, these are defaults) ---
// N=25000 nodes, E=400000 edges, F_IN=64, HID=128, HEADS=4, OUT=256

#define LRELU(x) ((x) > 0.f ? (x) : 0.2f * (x))

// ---------------- CSR build ----------------
__global__ void deg_count_kernel(const int* __restrict__ ei, int E, int N, int* __restrict__ deg) {
    int i = blockIdx.x * blockDim.x + threadIdx.x;
    if (i < E) {
        atomicAdd(&deg[ei[E + i]], 1);       // dst of real edge
    } else if (i < E + N) {
        atomicAdd(&deg[i - E], 1);           // self loop
    }
}

__global__ void csr_scan_kernel(const int* __restrict__ deg, int* __restrict__ rowptr, int N) {
    __shared__ int sums[256];
    __shared__ int offs[256];
    int t = threadIdx.x;
    int chunk = (N + 255) / 256;
    int s = t * chunk;
    int e = min(N, s + chunk);
    int local = 0;
    for (int i = s; i < e; i++) local += deg[i];
    sums[t] = local;
    __syncthreads();
    if (t == 0) {
        int run = 0;
        for (int i = 0; i < 256; i++) { offs[i] = run; run += sums[i]; }
        rowptr[N] = run;
    }
    __syncthreads();
    int run = offs[t];
    for (int i = s; i < e; i++) { rowptr[i] = run; run += deg[i]; }
}

__global__ void scatter_kernel(const int* __restrict__ ei, int E, int N,
                               const int* __restrict__ rowptr, int* __restrict__ cursor,
                               int* __restrict__ esrc) {
    int i = blockIdx.x * blockDim.x + threadIdx.x;
    int s, d;
    if (i < E) { s = ei[i]; d = ei[E + i]; }
    else if (i < E + N) { s = i - E; d = s; }
    else return;
    int pos = rowptr[d] + atomicAdd(&cursor[d], 1);
    esrc[pos] = s;
}

// ---------------- f32 tiled GEMM: C[M,Nn] = A[M,K] @ B[K,Nn] (+bias, +act) ----
// ACT: 0 = none, 1 = relu
template <int ACT>
__global__ __launch_bounds__(256) void gemm_f32(const float* __restrict__ A,
                                                const float* __restrict__ B,
                                                const float* __restrict__ bias,
                                                float* __restrict__ C,
                                                int M, int Nn, int K) {
    __shared__ float As[16][68];  // As[k][m]
    __shared__ float Bs[16][68];  // Bs[k][n]
    int tid = threadIdx.x;
    int tx = tid & 15, ty = tid >> 4;
    int row0 = blockIdx.y * 64, col0 = blockIdx.x * 64;
    float acc[4][4] = {};

    for (int k0 = 0; k0 < K; k0 += 16) {
        {
            int m = tid >> 2;
            int kk = (tid & 3) * 4;
            int gr = row0 + m;
            float4 v = make_float4(0.f, 0.f, 0.f, 0.f);
            if (gr < M) v = *(const float4*)&A[(size_t)gr * K + k0 + kk];
            As[kk + 0][m] = v.x; As[kk + 1][m] = v.y; As[kk + 2][m] = v.z; As[kk + 3][m] = v.w;

            int kr = tid >> 4;
            int nn = (tid & 15) * 4;
            float4 w = *(const float4*)&B[(size_t)(k0 + kr) * Nn + col0 + nn];
            *(float4*)&Bs[kr][nn] = w;
        }
        __syncthreads();
#pragma unroll
        for (int k = 0; k < 16; k++) {
            float a[4], b[4];
#pragma unroll
            for (int i = 0; i < 4; i++) a[i] = As[k][ty * 4 + i];
#pragma unroll
            for (int j = 0; j < 4; j++) b[j] = Bs[k][tx * 4 + j];
#pragma unroll
            for (int i = 0; i < 4; i++)
#pragma unroll
                for (int j = 0; j < 4; j++) acc[i][j] += a[i] * b[j];
        }
        __syncthreads();
    }
#pragma unroll
    for (int i = 0; i < 4; i++) {
        int gr = row0 + ty * 4 + i;
        if (gr >= M) continue;
        int gc = col0 + tx * 4;
        float4 v;
        float* vp = (float*)&v;
#pragma unroll
        for (int j = 0; j < 4; j++) {
            float t = acc[i][j];
            if (bias) t += bias[gc + j];
            if (ACT == 1) t = t > 0.f ? t : 0.f;
            vp[j] = t;
        }
        *(float4*)&C[(size_t)gr * Nn + gc] = v;
    }
}

// ---------------- alpha_src/alpha_dst: per-node dot products ------------------
template <int H>
__global__ __launch_bounds__(128) void alpha_kernel(const float* __restrict__ h,
                                                    const float* __restrict__ a_src,
                                                    const float* __restrict__ a_dst,
                                                    float* __restrict__ as_out,
                                                    float* __restrict__ ad_out) {
    int n = blockIdx.x;
    int tid = threadIdx.x;
    __shared__ float red[256];
#pragma unroll
    for (int hh = 0; hh < H; hh++) {
        float v = h[(size_t)n * (H * 128) + hh * 128 + tid];
        red[tid] = v * a_src[hh * 128 + tid];
        red[128 + tid] = v * a_dst[hh * 128 + tid];
        __syncthreads();
        for (int off = 64; off >= 1; off >>= 1) {
            if (tid < off) {
                red[tid] += red[tid + off];
                red[128 + tid] += red[128 + tid + off];
            }
            __syncthreads();
        }
        if (tid == 0) {
            as_out[n * H + hh] = red[0];
            ad_out[n * H + hh] = red[128];
        }
        __syncthreads();
    }
}

// ---------------- GAT aggregation, layer 1 (H=4, C=128), block=512 ------------
__global__ __launch_bounds__(512) void gat_agg_l1(const float* __restrict__ hpre,
                                                  const float* __restrict__ as,
                                                  const float* __restrict__ ad,
                                                  const int* __restrict__ rowptr,
                                                  const int* __restrict__ esrc,
                                                  const float* __restrict__ bias,
                                                  float* __restrict__ out) {
    int n = blockIdx.x;
    int tid = threadIdx.x;
    int begin = rowptr[n], end = rowptr[n + 1];
    int deg = end - begin;
    __shared__ float red[512];
    __shared__ float sm[4];
    __shared__ float sinv[4];
    __shared__ float wlds[128 * 4];
    __shared__ int slds[128];

    int h = tid & 3;
    float adh = ad[n * 4 + h];

    // phase A: segment max per head
    float lmax = -3.4e38f;
    for (int j = (tid >> 2); j < deg; j += 128) {
        int s = esrc[begin + j];
        float e = as[s * 4 + h] + adh;
        e = LRELU(e);
        lmax = fmaxf(lmax, e);
    }
    red[tid] = lmax;
    __syncthreads();
    for (int off = 256; off >= 4; off >>= 1) {
        if (tid < off) red[tid] = fmaxf(red[tid], red[tid + off]);
        __syncthreads();
    }
    if (tid < 4) sm[tid] = red[tid];
    __syncthreads();
    float mh = sm[h];

    // phase B: sum of exp
    float lsum = 0.f;
    for (int j = (tid >> 2); j < deg; j += 128) {
        int s = esrc[begin + j];
        float e = as[s * 4 + h] + adh;
        e = LRELU(e);
        lsum += __expf(e - mh);
    }
    __syncthreads();
    red[tid] = lsum;
    __syncthreads();
    for (int off = 256; off >= 4; off >>= 1) {
        if (tid < off) red[tid] += red[tid + off];
        __syncthreads();
    }
    if (tid < 4) sinv[tid] = 1.f / (red[tid] + 1e-16f);
    __syncthreads();

    // phase C: weighted aggregate, tiled over edges
    float acc = 0.f;
    int myh = tid >> 7;  // head owning feature tid
    for (int t0 = begin; t0 < end; t0 += 128) {
        int tn = min(128, end - t0);
        if (tid < tn * 4) {
            int j = tid >> 2;
            int hh = tid & 3;
            int s = esrc[t0 + j];
            if (hh == 0) slds[j] = s;
            float e = as[s * 4 + hh] + ad[n * 4 + hh];
            e = LRELU(e);
            wlds[(j << 2) + hh] = __expf(e - sm[hh]) * sinv[hh];
        }
        __syncthreads();
        for (int j = 0; j < tn; j++) {
            acc += wlds[(j << 2) + myh] * hpre[(size_t)slds[j] * 512 + tid];
        }
        __syncthreads();
    }
    float v = acc + bias[tid];
    out[(size_t)n * 512 + tid] = v > 0.f ? v : (__expf(v) - 1.f);  // ELU
}

// ---------------- GAT aggregation, layer 2 (H=1, C=128), block=128 ------------
__global__ __launch_bounds__(128) void gat_agg_l2(const float* __restrict__ hpre,
                                                  const float* __restrict__ as,
                                                  const float* __restrict__ ad,
                                                  const int* __restrict__ rowptr,
                                                  const int* __restrict__ esrc,
                                                  const float* __restrict__ bias,
                                                  float* __restrict__ out) {
    int n = blockIdx.x;
    int tid = threadIdx.x;
    int begin = rowptr[n], end = rowptr[n + 1];
    int deg = end - begin;
    __shared__ float red[128];
    __shared__ float smv, sinvv;
    __shared__ float wlds[128];
    __shared__ int slds[128];

    float adh = ad[n];
    float lmax = -3.4e38f;
    for (int j = tid; j < deg; j += 128) {
        float e = as[esrc[begin + j]] + adh;
        e = LRELU(e);
        lmax = fmaxf(lmax, e);
    }
    red[tid] = lmax;
    __syncthreads();
    for (int off = 64; off >= 1; off >>= 1) {
        if (tid < off) red[tid] = fmaxf(red[tid], red[tid + off]);
        __syncthreads();
    }
    if (tid == 0) smv = red[0];
    __syncthreads();
    float mh = smv;

    float lsum = 0.f;
    for (int j = tid; j < deg; j += 128) {
        float e = as[esrc[begin + j]] + adh;
        e = LRELU(e);
        lsum += __expf(e - mh);
    }
    __syncthreads();
    red[tid] = lsum;
    __syncthreads();
    for (int off = 64; off >= 1; off >>= 1) {
        if (tid < off) red[tid] += red[tid + off];
        __syncthreads();
    }
    if (tid == 0) sinvv = 1.f / (red[0] + 1e-16f);
    __syncthreads();
    float inv = sinvv;

    float acc = 0.f;
    for (int t0 = begin; t0 < end; t0 += 128) {
        int tn = min(128, end - t0);
        if (tid < tn) {
            int s = esrc[t0 + tid];
            slds[tid] = s;
            float e = as[s] + adh;
            e = LRELU(e);
            wlds[tid] = __expf(e - mh) * inv;
        }
        __syncthreads();
        for (int j = 0; j < tn; j++) {
            acc += wlds[j] * hpre[(size_t)slds[j] * 128 + tid];
        }
        __syncthreads();
    }
    float v = acc + bias[tid];
    out[(size_t)n * 128 + tid] = v > 0.f ? v : (__expf(v) - 1.f);  // ELU
}

// ---------------- mean pool (partial sums + atomics) --------------------------
__global__ __launch_bounds__(128) void pool_sum_kernel(const float* __restrict__ o2,
                                                       float* __restrict__ pool, int N) {
    int f = threadIdx.x;  // 128 features
    int r0 = blockIdx.x * 256;
    int r1 = min(N, r0 + 256);
    float acc = 0.f;
    for (int r = r0; r < r1; r++) acc += o2[(size_t)r * 128 + f];
    atomicAdd(&pool[f], acc);
}

// ---------------- final GEMV: out[256] = mean(h) @ W_out + b_out --------------
__global__ __launch_bounds__(256) void final_out_kernel(const float* __restrict__ pool,
                                                        const float* __restrict__ Wout,
                                                        const float* __restrict__ bout,
                                                        float* __restrict__ out, float invN) {
    int o = threadIdx.x;  // 256
    float acc = 0.f;
    for (int k = 0; k < 128; k++) acc += pool[k] * Wout[k * 256 + o];
    out[o] = acc * invN + bout[o];
}

// ---------------- launch ------------------------------------------------------
extern "C" void kernel_launch(void* const* d_in, const int* in_sizes, int n_in,
                              void* d_out, int out_size, void* d_ws, size_t ws_size,
                              hipStream_t stream) {
    const float* x      = (const float*)d_in[0];
    const int*   ei     = (const int*)d_in[1];
    const float* W_emb  = (const float*)d_in[2];
    const float* b_emb  = (const float*)d_in[3];
    const float* W1     = (const float*)d_in[4];
    const float* a1_src = (const float*)d_in[5];
    const float* a1_dst = (const float*)d_in[6];
    const float* b1     = (const float*)d_in[7];
    const float* W2     = (const float*)d_in[8];
    const float* a2_src = (const float*)d_in[9];
    const float* a2_dst = (const float*)d_in[10];
    const float* b2     = (const float*)d_in[11];
    const float* W_out  = (const float*)d_in[12];
    const float* b_out  = (const float*)d_in[13];
    float* out = (float*)d_out;

    const int N = in_sizes[0] / 64;   // 25000
    const int E = in_sizes[1] / 2;    // 400000
    const int Etot = E + N;

    // workspace carve-up (256B aligned)
    char* ws = (char*)d_ws;
    size_t off = 0;
    auto alloc = [&](size_t bytes) -> void* {
        void* p = ws + off;
        off = (off + bytes + 255) & ~(size_t)255;
        return p;
    };
    float* h0    = (float*)alloc((size_t)N * 128 * 4);
    float* h1pre = (float*)alloc((size_t)N * 512 * 4);
    float* o1    = (float*)alloc((size_t)N * 512 * 4);
    float* h2pre = (float*)alloc((size_t)N * 128 * 4);
    float* o2    = (float*)alloc((size_t)N * 128 * 4);
    float* as1   = (float*)alloc((size_t)N * 4 * 4);
    float* ad1   = (float*)alloc((size_t)N * 4 * 4);
    float* as2   = (float*)alloc((size_t)N * 4);
    float* ad2   = (float*)alloc((size_t)N * 4);
    float* pool  = (float*)alloc(128 * 4);
    int* rowptr  = (int*)alloc((size_t)(N + 1) * 4);
    int* deg     = (int*)alloc((size_t)N * 4);
    int* cursor  = (int*)alloc((size_t)N * 4);
    int* esrc    = (int*)alloc((size_t)Etot * 4);

    // zero the accumulating buffers (ws is poisoned 0xAA before every launch)
    hipMemsetAsync(deg, 0, (size_t)N * 4, stream);
    hipMemsetAsync(cursor, 0, (size_t)N * 4, stream);
    hipMemsetAsync(pool, 0, 128 * 4, stream);

    // CSR build
    int blocksE = (Etot + 255) / 256;
    deg_count_kernel<<<blocksE, 256, 0, stream>>>(ei, E, N, deg);
    csr_scan_kernel<<<1, 256, 0, stream>>>(deg, rowptr, N);
    scatter_kernel<<<blocksE, 256, 0, stream>>>(ei, E, N, rowptr, cursor, esrc);

    // h0 = relu(x @ W_emb + b_emb)   [N,128]
    {
        dim3 grid(128 / 64, (N + 63) / 64);
        gemm_f32<1><<<grid, 256, 0, stream>>>(x, W_emb, b_emb, h0, N, 128, 64);
    }
    // h1pre = h0 @ W1   [N,512]
    {
        dim3 grid(512 / 64, (N + 63) / 64);
        gemm_f32<0><<<grid, 256, 0, stream>>>(h0, W1, nullptr, h1pre, N, 512, 128);
    }
    // attention coefficients, layer 1
    alpha_kernel<4><<<N, 128, 0, stream>>>(h1pre, a1_src, a1_dst, as1, ad1);
    // aggregate layer 1 -> o1 = elu(agg + b1)  [N,512]
    gat_agg_l1<<<N, 512, 0, stream>>>(h1pre, as1, ad1, rowptr, esrc, b1, o1);

    // h2pre = o1 @ W2   [N,128]
    {
        dim3 grid(128 / 64, (N + 63) / 64);
        gemm_f32<0><<<grid, 256, 0, stream>>>(o1, W2, nullptr, h2pre, N, 128, 512);
    }
    // attention coefficients, layer 2
    alpha_kernel<1><<<N, 128, 0, stream>>>(h2pre, a2_src, a2_dst, as2, ad2);
    // aggregate layer 2 -> o2 = elu(agg + b2)  [N,128]
    gat_agg_l2<<<N, 128, 0, stream>>>(h2pre, as2, ad2, rowptr, esrc, b2, o2);

    // mean pool + final GEMV
    pool_sum_kernel<<<(N + 255) / 256, 128, 0, stream>>>(o2, pool, N);
    final_out_kernel<<<1, 256, 0, stream>>>(pool, W_out, b_out, out, 1.f / (float)N);
}

// Round 2
// 507.678 us; speedup vs baseline: 1.1815x; 1.1815x over previous
//
#include <hip/hip_runtime.h>
#include <hip/hip_bf16.h>

// N=25000 nodes, E=400000 edges (+N self loops), F_IN=64, HID=128, HEADS=4, OUT=256
// Strategy: bf16 interior (MFMA GEMMs + bf16 gathers), f32 softmax/accum/pool.

#define LRELU(x) ((x) > 0.f ? (x) : 0.2f * (x))

typedef short bf16x8 __attribute__((ext_vector_type(8)));
typedef float f32x4 __attribute__((ext_vector_type(4)));

__device__ __forceinline__ unsigned short f2b(float f) {
    union { float f; unsigned u; } x; x.f = f;
    unsigned r = x.u + 0x7fff + ((x.u >> 16) & 1);
    return (unsigned short)(r >> 16);
}
__device__ __forceinline__ float b2f(unsigned short u) {
    union { unsigned u; float f; } x; x.u = ((unsigned)u) << 16;
    return x.f;
}

// ---------------- CSR build ----------------
__global__ void deg_count_kernel(const int* __restrict__ ei, int E, int N, int* __restrict__ deg) {
    int i = blockIdx.x * blockDim.x + threadIdx.x;
    if (i < E) {
        atomicAdd(&deg[ei[E + i]], 1);
    } else if (i < E + N) {
        atomicAdd(&deg[i - E], 1);
    }
}

__global__ void csr_scan_kernel(const int* __restrict__ deg, int* __restrict__ rowptr, int N) {
    __shared__ int sums[256];
    __shared__ int offs[256];
    int t = threadIdx.x;
    int chunk = (N + 255) / 256;
    int s = t * chunk;
    int e = min(N, s + chunk);
    int local = 0;
    for (int i = s; i < e; i++) local += deg[i];
    sums[t] = local;
    __syncthreads();
    if (t == 0) {
        int run = 0;
        for (int i = 0; i < 256; i++) { offs[i] = run; run += sums[i]; }
        rowptr[N] = run;
    }
    __syncthreads();
    int run = offs[t];
    for (int i = s; i < e; i++) { rowptr[i] = run; run += deg[i]; }
}

__global__ void scatter_kernel(const int* __restrict__ ei, int E, int N,
                               const int* __restrict__ rowptr, int* __restrict__ cursor,
                               int* __restrict__ esrc) {
    int i = blockIdx.x * blockDim.x + threadIdx.x;
    int s, d;
    if (i < E) { s = ei[i]; d = ei[E + i]; }
    else if (i < E + N) { s = i - E; d = s; }
    else return;
    int pos = rowptr[d] + atomicAdd(&cursor[d], 1);
    esrc[pos] = s;
}

// ---------------- conversion helpers -----------------------------------------
__global__ void conv_bf16_kernel(const float* __restrict__ in, unsigned short* __restrict__ out, int n) {
    int i = blockIdx.x * blockDim.x + threadIdx.x;
    if (i < n) out[i] = f2b(in[i]);
}

// in: [K][N] f32 row-major; out: [N][K] bf16 (transposed)
__global__ void transpose_conv_kernel(const float* __restrict__ in, unsigned short* __restrict__ out,
                                      int K, int N) {
    int i = blockIdx.x * blockDim.x + threadIdx.x;
    if (i < K * N) {
        int k = i / N, n = i - k * N;
        out[(size_t)n * K + k] = f2b(in[i]);
    }
}

// ---------------- MFMA bf16 NT GEMM: C[M,N] = A[M,K] @ Bt[N,K]^T --------------
// 128x128 tile, BK=32, 4 waves, each wave 64x64 via 4x4 of 16x16x32 MFMA.
// ACT: 0=none, 1=relu. Output bf16. bias optional (f32, length N).
template <int ACT>
__global__ __launch_bounds__(256) void gemm_mfma_nt(const unsigned short* __restrict__ A,
                                                    const unsigned short* __restrict__ Bt,
                                                    const float* __restrict__ bias,
                                                    unsigned short* __restrict__ C,
                                                    int M, int N, int K) {
    __shared__ __align__(16) unsigned short As[128 * 40];  // [row][k], pad 40 (80B = 20 banks)
    __shared__ __align__(16) unsigned short Bs[128 * 40];
    int tid = threadIdx.x;
    int gm0 = blockIdx.y * 128, gn0 = blockIdx.x * 128;
    int w = tid >> 6, lane = tid & 63;
    int wrow = (w >> 1) * 64, wcol = (w & 1) * 64;
    int l15 = lane & 15, quad = lane >> 4;

    f32x4 acc[4][4];
#pragma unroll
    for (int i = 0; i < 4; i++)
#pragma unroll
        for (int j = 0; j < 4; j++) acc[i][j] = {0.f, 0.f, 0.f, 0.f};

    for (int k0 = 0; k0 < K; k0 += 32) {
#pragma unroll
        for (int rr = 0; rr < 2; rr++) {
            int lin = tid + rr * 256;
            int row = lin >> 2;
            int cg = (lin & 3) * 8;
            int grow = gm0 + row; if (grow >= M) grow = M - 1;
            uint4 va = *(const uint4*)&A[(size_t)grow * K + k0 + cg];
            *(uint4*)&As[row * 40 + cg] = va;
            uint4 vb = *(const uint4*)&Bt[(size_t)(gn0 + row) * K + k0 + cg];
            *(uint4*)&Bs[row * 40 + cg] = vb;
        }
        __syncthreads();
        bf16x8 af[4], bfr[4];
#pragma unroll
        for (int i = 0; i < 4; i++) {
            af[i]  = *(const bf16x8*)&As[(wrow + i * 16 + l15) * 40 + quad * 8];
            bfr[i] = *(const bf16x8*)&Bs[(wcol + i * 16 + l15) * 40 + quad * 8];
        }
#pragma unroll
        for (int i = 0; i < 4; i++)
#pragma unroll
            for (int j = 0; j < 4; j++)
                acc[i][j] = __builtin_amdgcn_mfma_f32_16x16x32_bf16(af[i], bfr[j], acc[i][j], 0, 0, 0);
        __syncthreads();
    }

#pragma unroll
    for (int i = 0; i < 4; i++) {
        int row = gm0 + wrow + i * 16 + quad * 4;
#pragma unroll
        for (int j = 0; j < 4; j++) {
            int col = gn0 + wcol + j * 16 + l15;
            float bv = bias ? bias[col] : 0.f;
#pragma unroll
            for (int r = 0; r < 4; r++) {
                int gr = row + r;
                if (gr < M) {
                    float v = acc[i][j][r] + bv;
                    if (ACT == 1) v = fmaxf(v, 0.f);
                    C[(size_t)gr * N + col] = f2b(v);
                }
            }
        }
    }
}

// ---------------- alpha: one wave per node, bf16 row, shuffle reduce ----------
template <int H>
__global__ __launch_bounds__(256) void alpha_wave_kernel(const unsigned short* __restrict__ hb,
                                                         const float* __restrict__ a_src,
                                                         const float* __restrict__ a_dst,
                                                         float* __restrict__ as_out,
                                                         float* __restrict__ ad_out, int N) {
    int wid = (blockIdx.x * 256 + threadIdx.x) >> 6;  // node
    int lane = threadIdx.x & 63;
    if (wid >= N) return;
    const int F = H * 128;
    float ds = 0.f, dd = 0.f;
    if (lane * 8 < F) {
        uint4 v = *(const uint4*)&hb[(size_t)wid * F + lane * 8];
        unsigned uu[4] = {v.x, v.y, v.z, v.w};
#pragma unroll
        for (int t = 0; t < 4; t++) {
            union { unsigned u; float f; } f0, f1;
            f0.u = uu[t] << 16;
            f1.u = uu[t] & 0xffff0000u;
            int c = lane * 8 + 2 * t;
            ds += f0.f * a_src[c] + f1.f * a_src[c + 1];
            dd += f0.f * a_dst[c] + f1.f * a_dst[c + 1];
        }
    }
#pragma unroll
    for (int o = 1; o < 16; o <<= 1) {
        ds += __shfl_xor(ds, o);
        dd += __shfl_xor(dd, o);
    }
    if ((lane & 15) == 0) {
        int h = lane >> 4;
        if (h < H) {
            as_out[wid * H + h] = ds;
            ad_out[wid * H + h] = dd;
        }
    }
}

// ---------------- GAT aggregation, layer 1 (H=4, C=128), block=512 ------------
__global__ __launch_bounds__(512) void gat_agg_l1(const unsigned short* __restrict__ hpre,
                                                  const float* __restrict__ as,
                                                  const float* __restrict__ ad,
                                                  const int* __restrict__ rowptr,
                                                  const int* __restrict__ esrc,
                                                  const float* __restrict__ bias,
                                                  unsigned short* __restrict__ out) {
    int n = blockIdx.x;
    int tid = threadIdx.x;
    int begin = rowptr[n], end = rowptr[n + 1];
    int deg = end - begin;
    __shared__ float red[512];
    __shared__ float sm[4];
    __shared__ float sinv[4];
    __shared__ float wlds[128 * 4];
    __shared__ int slds[128];

    int h = tid & 3;
    float adh = ad[n * 4 + h];

    // phase A: segment max per head
    float lmax = -3.4e38f;
    for (int j = (tid >> 2); j < deg; j += 128) {
        int s = esrc[begin + j];
        float e = as[s * 4 + h] + adh;
        e = LRELU(e);
        lmax = fmaxf(lmax, e);
    }
    red[tid] = lmax;
    __syncthreads();
    for (int off = 256; off >= 4; off >>= 1) {
        if (tid < off) red[tid] = fmaxf(red[tid], red[tid + off]);
        __syncthreads();
    }
    if (tid < 4) sm[tid] = red[tid];
    __syncthreads();
    float mh = sm[h];

    // phase B: sum of exp
    float lsum = 0.f;
    for (int j = (tid >> 2); j < deg; j += 128) {
        int s = esrc[begin + j];
        float e = as[s * 4 + h] + adh;
        e = LRELU(e);
        lsum += __expf(e - mh);
    }
    __syncthreads();
    red[tid] = lsum;
    __syncthreads();
    for (int off = 256; off >= 4; off >>= 1) {
        if (tid < off) red[tid] += red[tid + off];
        __syncthreads();
    }
    if (tid < 4) sinv[tid] = 1.f / (red[tid] + 1e-16f);
    __syncthreads();

    // phase C: weighted aggregate (bf16 gather), tiled over edges
    float acc = 0.f;
    int myh = tid >> 7;
    for (int t0 = begin; t0 < end; t0 += 128) {
        int tn = min(128, end - t0);
        if (tid < tn * 4) {
            int j = tid >> 2;
            int hh = tid & 3;
            int s = esrc[t0 + j];
            if (hh == 0) slds[j] = s;
            float e = as[s * 4 + hh] + ad[n * 4 + hh];
            e = LRELU(e);
            wlds[(j << 2) + hh] = __expf(e - sm[hh]) * sinv[hh];
        }
        __syncthreads();
        for (int j = 0; j < tn; j++) {
            acc += wlds[(j << 2) + myh] * b2f(hpre[(size_t)slds[j] * 512 + tid]);
        }
        __syncthreads();
    }
    float v = acc + bias[tid];
    v = v > 0.f ? v : (__expf(v) - 1.f);  // ELU
    out[(size_t)n * 512 + tid] = f2b(v);
}

// ---------------- GAT aggregation, layer 2 (H=1, C=128), block=128 ------------
__global__ __launch_bounds__(128) void gat_agg_l2(const unsigned short* __restrict__ hpre,
                                                  const float* __restrict__ as,
                                                  const float* __restrict__ ad,
                                                  const int* __restrict__ rowptr,
                                                  const int* __restrict__ esrc,
                                                  const float* __restrict__ bias,
                                                  float* __restrict__ out) {
    int n = blockIdx.x;
    int tid = threadIdx.x;
    int begin = rowptr[n], end = rowptr[n + 1];
    int deg = end - begin;
    __shared__ float red[128];
    __shared__ float smv, sinvv;
    __shared__ float wlds[128];
    __shared__ int slds[128];

    float adh = ad[n];
    float lmax = -3.4e38f;
    for (int j = tid; j < deg; j += 128) {
        float e = as[esrc[begin + j]] + adh;
        e = LRELU(e);
        lmax = fmaxf(lmax, e);
    }
    red[tid] = lmax;
    __syncthreads();
    for (int off = 64; off >= 1; off >>= 1) {
        if (tid < off) red[tid] = fmaxf(red[tid], red[tid + off]);
        __syncthreads();
    }
    if (tid == 0) smv = red[0];
    __syncthreads();
    float mh = smv;

    float lsum = 0.f;
    for (int j = tid; j < deg; j += 128) {
        float e = as[esrc[begin + j]] + adh;
        e = LRELU(e);
        lsum += __expf(e - mh);
    }
    __syncthreads();
    red[tid] = lsum;
    __syncthreads();
    for (int off = 64; off >= 1; off >>= 1) {
        if (tid < off) red[tid] += red[tid + off];
        __syncthreads();
    }
    if (tid == 0) sinvv = 1.f / (red[0] + 1e-16f);
    __syncthreads();
    float inv = sinvv;

    float acc = 0.f;
    for (int t0 = begin; t0 < end; t0 += 128) {
        int tn = min(128, end - t0);
        if (tid < tn) {
            int s = esrc[t0 + tid];
            slds[tid] = s;
            float e = as[s] + adh;
            e = LRELU(e);
            wlds[tid] = __expf(e - mh) * inv;
        }
        __syncthreads();
        for (int j = 0; j < tn; j++) {
            acc += wlds[j] * b2f(hpre[(size_t)slds[j] * 128 + tid]);
        }
        __syncthreads();
    }
    float v = acc + bias[tid];
    out[(size_t)n * 128 + tid] = v > 0.f ? v : (__expf(v) - 1.f);  // ELU
}

// ---------------- mean pool + final GEMV --------------------------------------
__global__ __launch_bounds__(128) void pool_sum_kernel(const float* __restrict__ o2,
                                                       float* __restrict__ pool, int N) {
    int f = threadIdx.x;
    int r0 = blockIdx.x * 256;
    int r1 = min(N, r0 + 256);
    float acc = 0.f;
    for (int r = r0; r < r1; r++) acc += o2[(size_t)r * 128 + f];
    atomicAdd(&pool[f], acc);
}

__global__ __launch_bounds__(256) void final_out_kernel(const float* __restrict__ pool,
                                                        const float* __restrict__ Wout,
                                                        const float* __restrict__ bout,
                                                        float* __restrict__ out, float invN) {
    int o = threadIdx.x;
    float acc = 0.f;
    for (int k = 0; k < 128; k++) acc += pool[k] * Wout[k * 256 + o];
    out[o] = acc * invN + bout[o];
}

// ---------------- launch ------------------------------------------------------
extern "C" void kernel_launch(void* const* d_in, const int* in_sizes, int n_in,
                              void* d_out, int out_size, void* d_ws, size_t ws_size,
                              hipStream_t stream) {
    const float* x      = (const float*)d_in[0];
    const int*   ei     = (const int*)d_in[1];
    const float* W_emb  = (const float*)d_in[2];
    const float* b_emb  = (const float*)d_in[3];
    const float* W1     = (const float*)d_in[4];
    const float* a1_src = (const float*)d_in[5];
    const float* a1_dst = (const float*)d_in[6];
    const float* b1     = (const float*)d_in[7];
    const float* W2     = (const float*)d_in[8];
    const float* a2_src = (const float*)d_in[9];
    const float* a2_dst = (const float*)d_in[10];
    const float* b2     = (const float*)d_in[11];
    const float* W_out  = (const float*)d_in[12];
    const float* b_out  = (const float*)d_in[13];
    float* out = (float*)d_out;

    const int N = in_sizes[0] / 64;   // 25000
    const int E = in_sizes[1] / 2;    // 400000
    const int Etot = E + N;

    char* ws = (char*)d_ws;
    size_t off = 0;
    auto alloc = [&](size_t bytes) -> void* {
        void* p = ws + off;
        off = (off + bytes + 255) & ~(size_t)255;
        return p;
    };
    typedef unsigned short u16;
    u16* xb    = (u16*)alloc((size_t)N * 64 * 2);
    u16* WeT   = (u16*)alloc((size_t)128 * 64 * 2);
    u16* W1T   = (u16*)alloc((size_t)512 * 128 * 2);
    u16* W2T   = (u16*)alloc((size_t)128 * 512 * 2);
    u16* h0b   = (u16*)alloc((size_t)N * 128 * 2);
    u16* h1b   = (u16*)alloc((size_t)N * 512 * 2);
    u16* o1b   = (u16*)alloc((size_t)N * 512 * 2);
    u16* h2b   = (u16*)alloc((size_t)N * 128 * 2);
    float* o2  = (float*)alloc((size_t)N * 128 * 4);
    float* as1 = (float*)alloc((size_t)N * 4 * 4);
    float* ad1 = (float*)alloc((size_t)N * 4 * 4);
    float* as2 = (float*)alloc((size_t)N * 4);
    float* ad2 = (float*)alloc((size_t)N * 4);
    float* pool = (float*)alloc(128 * 4);
    int* rowptr = (int*)alloc((size_t)(N + 1) * 4);
    int* deg    = (int*)alloc((size_t)N * 4);
    int* cursor = (int*)alloc((size_t)N * 4);
    int* esrc   = (int*)alloc((size_t)Etot * 4);

    hipMemsetAsync(deg, 0, (size_t)N * 4, stream);
    hipMemsetAsync(cursor, 0, (size_t)N * 4, stream);
    hipMemsetAsync(pool, 0, 128 * 4, stream);

    // CSR build
    int blocksE = (Etot + 255) / 256;
    deg_count_kernel<<<blocksE, 256, 0, stream>>>(ei, E, N, deg);
    csr_scan_kernel<<<1, 256, 0, stream>>>(deg, rowptr, N);
    scatter_kernel<<<blocksE, 256, 0, stream>>>(ei, E, N, rowptr, cursor, esrc);

    // bf16 conversions / weight transposes
    conv_bf16_kernel<<<(N * 64 + 255) / 256, 256, 0, stream>>>(x, xb, N * 64);
    transpose_conv_kernel<<<(64 * 128 + 255) / 256, 256, 0, stream>>>(W_emb, WeT, 64, 128);
    transpose_conv_kernel<<<(128 * 512 + 255) / 256, 256, 0, stream>>>(W1, W1T, 128, 512);
    transpose_conv_kernel<<<(512 * 128 + 255) / 256, 256, 0, stream>>>(W2, W2T, 512, 128);

    int mtiles = (N + 127) / 128;
    // h0 = relu(x @ W_emb + b_emb)  [N,128] bf16
    gemm_mfma_nt<1><<<dim3(1, mtiles), 256, 0, stream>>>(xb, WeT, b_emb, h0b, N, 128, 64);
    // h1pre = h0 @ W1  [N,512] bf16
    gemm_mfma_nt<0><<<dim3(4, mtiles), 256, 0, stream>>>(h0b, W1T, nullptr, h1b, N, 512, 128);

    // layer-1 attention + aggregation
    alpha_wave_kernel<4><<<(N * 64 + 255) / 256, 256, 0, stream>>>(h1b, a1_src, a1_dst, as1, ad1, N);
    gat_agg_l1<<<N, 512, 0, stream>>>(h1b, as1, ad1, rowptr, esrc, b1, o1b);

    // h2pre = o1 @ W2  [N,128] bf16
    gemm_mfma_nt<0><<<dim3(1, mtiles), 256, 0, stream>>>(o1b, W2T, nullptr, h2b, N, 128, 512);

    // layer-2 attention + aggregation
    alpha_wave_kernel<1><<<(N * 64 + 255) / 256, 256, 0, stream>>>(h2b, a2_src, a2_dst, as2, ad2, N);
    gat_agg_l2<<<N, 128, 0, stream>>>(h2b, as2, ad2, rowptr, esrc, b2, o2);

    // mean pool + final GEMV
    pool_sum_kernel<<<(N + 255) / 256, 128, 0, stream>>>(o2, pool, N);
    final_out_kernel<<<1, 256, 0, stream>>>(pool, W_out, b_out, out, 1.f / (float)N);
}

// Round 3
// 442.294 us; speedup vs baseline: 1.3561x; 1.1478x over previous
//
#include <hip/hip_runtime.h>
#include <hip/hip_bf16.h>

// N=25000 nodes, E=400000 edges (+N self loops), F_IN=64, HID=128, HEADS=4, OUT=256
// bf16 interior (MFMA GEMMs + vectorized bf16 gathers), f32 softmax/accum/pool.
// Aggregation: wave-per-edge-stripe, lane-per-feature-chunk (16B loads).

#define LRELU(x) ((x) > 0.f ? (x) : 0.2f * (x))

typedef short bf16x8 __attribute__((ext_vector_type(8)));
typedef float f32x4 __attribute__((ext_vector_type(4)));

__device__ __forceinline__ unsigned short f2b(float f) {
    union { float f; unsigned u; } x; x.f = f;
    unsigned r = x.u + 0x7fff + ((x.u >> 16) & 1);
    return (unsigned short)(r >> 16);
}
__device__ __forceinline__ float b2f(unsigned short u) {
    union { unsigned u; float f; } x; x.u = ((unsigned)u) << 16;
    return x.f;
}
__device__ __forceinline__ float blo(unsigned u) {
    union { unsigned u; float f; } x; x.u = u << 16; return x.f;
}
__device__ __forceinline__ float bhi(unsigned u) {
    union { unsigned u; float f; } x; x.u = u & 0xffff0000u; return x.f;
}

// ---------------- CSR build ----------------
__global__ void deg_count_kernel(const int* __restrict__ ei, int E, int N, int* __restrict__ deg) {
    int i = blockIdx.x * blockDim.x + threadIdx.x;
    if (i < E) {
        atomicAdd(&deg[ei[E + i]], 1);
    } else if (i < E + N) {
        atomicAdd(&deg[i - E], 1);
    }
}

__global__ void csr_scan_kernel(const int* __restrict__ deg, int* __restrict__ rowptr, int N) {
    __shared__ int sums[256];
    __shared__ int offs[256];
    int t = threadIdx.x;
    int chunk = (N + 255) / 256;
    int s = t * chunk;
    int e = min(N, s + chunk);
    int local = 0;
    for (int i = s; i < e; i++) local += deg[i];
    sums[t] = local;
    __syncthreads();
    if (t == 0) {
        int run = 0;
        for (int i = 0; i < 256; i++) { offs[i] = run; run += sums[i]; }
        rowptr[N] = run;
    }
    __syncthreads();
    int run = offs[t];
    for (int i = s; i < e; i++) { rowptr[i] = run; run += deg[i]; }
}

__global__ void scatter_kernel(const int* __restrict__ ei, int E, int N,
                               const int* __restrict__ rowptr, int* __restrict__ cursor,
                               int* __restrict__ esrc, int* __restrict__ edst) {
    int i = blockIdx.x * blockDim.x + threadIdx.x;
    int s, d;
    if (i < E) { s = ei[i]; d = ei[E + i]; }
    else if (i < E + N) { s = i - E; d = s; }
    else return;
    int pos = rowptr[d] + atomicAdd(&cursor[d], 1);
    esrc[pos] = s;
    edst[pos] = d;
}

// ---------------- per-edge logits (CSR order) ---------------------------------
__global__ void edge_e1_kernel(const int* __restrict__ esrc, const int* __restrict__ edst,
                               const float4* __restrict__ as4, const float4* __restrict__ ad4,
                               float4* __restrict__ eb, int Etot) {
    int i = blockIdx.x * blockDim.x + threadIdx.x;
    if (i >= Etot) return;
    float4 u = as4[esrc[i]];
    float4 v = ad4[edst[i]];
    float4 e;
    e.x = LRELU(u.x + v.x); e.y = LRELU(u.y + v.y);
    e.z = LRELU(u.z + v.z); e.w = LRELU(u.w + v.w);
    eb[i] = e;
}

__global__ void edge_e2_kernel(const int* __restrict__ esrc, const int* __restrict__ edst,
                               const float* __restrict__ as, const float* __restrict__ ad,
                               float* __restrict__ eb, int Etot) {
    int i = blockIdx.x * blockDim.x + threadIdx.x;
    if (i >= Etot) return;
    float e = as[esrc[i]] + ad[edst[i]];
    eb[i] = LRELU(e);
}

// ---------------- conversion helpers -----------------------------------------
__global__ void conv_bf16_kernel(const float* __restrict__ in, unsigned short* __restrict__ out, int n) {
    int i = blockIdx.x * blockDim.x + threadIdx.x;
    if (i < n) out[i] = f2b(in[i]);
}

__global__ void transpose_conv_kernel(const float* __restrict__ in, unsigned short* __restrict__ out,
                                      int K, int N) {
    int i = blockIdx.x * blockDim.x + threadIdx.x;
    if (i < K * N) {
        int k = i / N, n = i - k * N;
        out[(size_t)n * K + k] = f2b(in[i]);
    }
}

// ---------------- MFMA bf16 NT GEMM: C[M,N] = A[M,K] @ Bt[N,K]^T --------------
template <int ACT>
__global__ __launch_bounds__(256) void gemm_mfma_nt(const unsigned short* __restrict__ A,
                                                    const unsigned short* __restrict__ Bt,
                                                    const float* __restrict__ bias,
                                                    unsigned short* __restrict__ C,
                                                    int M, int N, int K) {
    __shared__ __align__(16) unsigned short As[128 * 40];
    __shared__ __align__(16) unsigned short Bs[128 * 40];
    int tid = threadIdx.x;
    int gm0 = blockIdx.y * 128, gn0 = blockIdx.x * 128;
    int w = tid >> 6, lane = tid & 63;
    int wrow = (w >> 1) * 64, wcol = (w & 1) * 64;
    int l15 = lane & 15, quad = lane >> 4;

    f32x4 acc[4][4];
#pragma unroll
    for (int i = 0; i < 4; i++)
#pragma unroll
        for (int j = 0; j < 4; j++) acc[i][j] = {0.f, 0.f, 0.f, 0.f};

    for (int k0 = 0; k0 < K; k0 += 32) {
#pragma unroll
        for (int rr = 0; rr < 2; rr++) {
            int lin = tid + rr * 256;
            int row = lin >> 2;
            int cg = (lin & 3) * 8;
            int grow = gm0 + row; if (grow >= M) grow = M - 1;
            uint4 va = *(const uint4*)&A[(size_t)grow * K + k0 + cg];
            *(uint4*)&As[row * 40 + cg] = va;
            uint4 vb = *(const uint4*)&Bt[(size_t)(gn0 + row) * K + k0 + cg];
            *(uint4*)&Bs[row * 40 + cg] = vb;
        }
        __syncthreads();
        bf16x8 af[4], bfr[4];
#pragma unroll
        for (int i = 0; i < 4; i++) {
            af[i]  = *(const bf16x8*)&As[(wrow + i * 16 + l15) * 40 + quad * 8];
            bfr[i] = *(const bf16x8*)&Bs[(wcol + i * 16 + l15) * 40 + quad * 8];
        }
#pragma unroll
        for (int i = 0; i < 4; i++)
#pragma unroll
            for (int j = 0; j < 4; j++)
                acc[i][j] = __builtin_amdgcn_mfma_f32_16x16x32_bf16(af[i], bfr[j], acc[i][j], 0, 0, 0);
        __syncthreads();
    }

#pragma unroll
    for (int i = 0; i < 4; i++) {
        int row = gm0 + wrow + i * 16 + quad * 4;
#pragma unroll
        for (int j = 0; j < 4; j++) {
            int col = gn0 + wcol + j * 16 + l15;
            float bv = bias ? bias[col] : 0.f;
#pragma unroll
            for (int r = 0; r < 4; r++) {
                int gr = row + r;
                if (gr < M) {
                    float v = acc[i][j][r] + bv;
                    if (ACT == 1) v = fmaxf(v, 0.f);
                    C[(size_t)gr * N + col] = f2b(v);
                }
            }
        }
    }
}

// ---------------- alpha: one wave per node, bf16 row, shuffle reduce ----------
template <int H>
__global__ __launch_bounds__(256) void alpha_wave_kernel(const unsigned short* __restrict__ hb,
                                                         const float* __restrict__ a_src,
                                                         const float* __restrict__ a_dst,
                                                         float* __restrict__ as_out,
                                                         float* __restrict__ ad_out, int N) {
    int wid = (blockIdx.x * 256 + threadIdx.x) >> 6;
    int lane = threadIdx.x & 63;
    if (wid >= N) return;
    const int F = H * 128;
    float ds = 0.f, dd = 0.f;
    if (lane * 8 < F) {
        uint4 v = *(const uint4*)&hb[(size_t)wid * F + lane * 8];
        unsigned uu[4] = {v.x, v.y, v.z, v.w};
#pragma unroll
        for (int t = 0; t < 4; t++) {
            float f0 = blo(uu[t]), f1 = bhi(uu[t]);
            int c = lane * 8 + 2 * t;
            ds += f0 * a_src[c] + f1 * a_src[c + 1];
            dd += f0 * a_dst[c] + f1 * a_dst[c + 1];
        }
    }
#pragma unroll
    for (int o = 1; o < 16; o <<= 1) {
        ds += __shfl_xor(ds, o);
        dd += __shfl_xor(dd, o);
    }
    if ((lane & 15) == 0) {
        int h = lane >> 4;
        if (h < H) {
            as_out[wid * H + h] = ds;
            ad_out[wid * H + h] = dd;
        }
    }
}

// ---------------- GAT aggregation L1 (H=4, C=128): wave-stripe gather ---------
__global__ __launch_bounds__(256) void gat_agg_l1(const unsigned short* __restrict__ hpre,
                                                  const float4* __restrict__ eb4,
                                                  const int* __restrict__ rowptr,
                                                  const int* __restrict__ esrc,
                                                  const float* __restrict__ bias,
                                                  unsigned short* __restrict__ out) {
    int n = blockIdx.x;
    int tid = threadIdx.x;
    int w = tid >> 6, lane = tid & 63;
    int begin = rowptr[n], end = rowptr[n + 1];
    int deg = end - begin;

    __shared__ float part[4 * 520];   // [w][t*65 + lane]
    __shared__ float redw[4][4];
    __shared__ float sm[4], sinv[4];

    // phase A: per-head max over edges (contiguous float4 stream)
    f32x4 lm = {-3.4e38f, -3.4e38f, -3.4e38f, -3.4e38f};
    for (int j = tid; j < deg; j += 256) {
        float4 e = eb4[begin + j];
        lm[0] = fmaxf(lm[0], e.x); lm[1] = fmaxf(lm[1], e.y);
        lm[2] = fmaxf(lm[2], e.z); lm[3] = fmaxf(lm[3], e.w);
    }
#pragma unroll
    for (int o = 32; o >= 1; o >>= 1) {
#pragma unroll
        for (int c = 0; c < 4; c++) lm[c] = fmaxf(lm[c], __shfl_xor(lm[c], o));
    }
    if (lane == 0) { redw[w][0] = lm[0]; redw[w][1] = lm[1]; redw[w][2] = lm[2]; redw[w][3] = lm[3]; }
    __syncthreads();
    if (tid < 4) {
        float m = fmaxf(fmaxf(redw[0][tid], redw[1][tid]), fmaxf(redw[2][tid], redw[3][tid]));
        sm[tid] = m;
    }
    __syncthreads();
    float m0 = sm[0], m1 = sm[1], m2 = sm[2], m3 = sm[3];

    // phase B: per-head sum of exp
    f32x4 ls = {0.f, 0.f, 0.f, 0.f};
    for (int j = tid; j < deg; j += 256) {
        float4 e = eb4[begin + j];
        ls[0] += __expf(e.x - m0); ls[1] += __expf(e.y - m1);
        ls[2] += __expf(e.z - m2); ls[3] += __expf(e.w - m3);
    }
#pragma unroll
    for (int o = 32; o >= 1; o >>= 1) {
#pragma unroll
        for (int c = 0; c < 4; c++) ls[c] += __shfl_xor(ls[c], o);
    }
    if (lane == 0) { redw[w][0] = ls[0]; redw[w][1] = ls[1]; redw[w][2] = ls[2]; redw[w][3] = ls[3]; }
    __syncthreads();
    if (tid < 4) {
        float s = redw[0][tid] + redw[1][tid] + redw[2][tid] + redw[3][tid];
        sinv[tid] = 1.f / (s + 1e-16f);
    }
    __syncthreads();

    // phase C: weighted gather; lane covers features lane*8..lane*8+7
    int h = lane >> 4;                 // head of this lane's features
    float mh = sm[h], invh = sinv[h];
    const float* ebf = (const float*)eb4;
    float acc[8] = {};
    for (int j = begin + w; j < end; j += 4) {
        int s = esrc[j];                       // wave-uniform (broadcast)
        float ev = ebf[(size_t)j * 4 + h];     // 16-lane broadcast
        float wgt = __expf(ev - mh) * invh;
        uint4 hv = *(const uint4*)&hpre[(size_t)s * 512 + lane * 8];
        acc[0] += wgt * blo(hv.x); acc[1] += wgt * bhi(hv.x);
        acc[2] += wgt * blo(hv.y); acc[3] += wgt * bhi(hv.y);
        acc[4] += wgt * blo(hv.z); acc[5] += wgt * bhi(hv.z);
        acc[6] += wgt * blo(hv.w); acc[7] += wgt * bhi(hv.w);
    }
    // cross-wave reduction: part[w][t*65 + lane]
#pragma unroll
    for (int t = 0; t < 8; t++) part[w * 520 + t * 65 + lane] = acc[t];
    __syncthreads();
#pragma unroll
    for (int f = tid; f < 512; f += 256) {
        int t = f & 7, l = f >> 3;
        float v = part[0 * 520 + t * 65 + l] + part[1 * 520 + t * 65 + l] +
                  part[2 * 520 + t * 65 + l] + part[3 * 520 + t * 65 + l];
        v += bias[f];
        v = v > 0.f ? v : (__expf(v) - 1.f);   // ELU
        out[(size_t)n * 512 + f] = f2b(v);
    }
}

// ---------------- GAT aggregation L2 (H=1, C=128): wave-stripe gather ---------
__global__ __launch_bounds__(256) void gat_agg_l2(const unsigned short* __restrict__ hpre,
                                                  const float* __restrict__ eb,
                                                  const int* __restrict__ rowptr,
                                                  const int* __restrict__ esrc,
                                                  const float* __restrict__ bias,
                                                  float* __restrict__ out) {
    int n = blockIdx.x;
    int tid = threadIdx.x;
    int w = tid >> 6, lane = tid & 63;
    int begin = rowptr[n], end = rowptr[n + 1];
    int deg = end - begin;

    __shared__ float part[4 * 130];   // [w][t*65 + lane]
    __shared__ float redw[4];
    __shared__ float smv, sinvv;

    float lm = -3.4e38f;
    for (int j = tid; j < deg; j += 256) lm = fmaxf(lm, eb[begin + j]);
#pragma unroll
    for (int o = 32; o >= 1; o >>= 1) lm = fmaxf(lm, __shfl_xor(lm, o));
    if (lane == 0) redw[w] = lm;
    __syncthreads();
    if (tid == 0) smv = fmaxf(fmaxf(redw[0], redw[1]), fmaxf(redw[2], redw[3]));
    __syncthreads();
    float mh = smv;

    float lsum = 0.f;
    for (int j = tid; j < deg; j += 256) lsum += __expf(eb[begin + j] - mh);
#pragma unroll
    for (int o = 32; o >= 1; o >>= 1) lsum += __shfl_xor(lsum, o);
    if (lane == 0) redw[w] = lsum;
    __syncthreads();
    if (tid == 0) sinvv = 1.f / (redw[0] + redw[1] + redw[2] + redw[3] + 1e-16f);
    __syncthreads();
    float inv = sinvv;

    float acc0 = 0.f, acc1 = 0.f;
    for (int j = begin + w; j < end; j += 4) {
        int s = esrc[j];
        float wgt = __expf(eb[j] - mh) * inv;
        unsigned hv = *(const unsigned*)&hpre[(size_t)s * 128 + lane * 2];
        acc0 += wgt * blo(hv);
        acc1 += wgt * bhi(hv);
    }
    part[w * 130 + 0 * 65 + lane] = acc0;
    part[w * 130 + 1 * 65 + lane] = acc1;
    __syncthreads();
    if (tid < 128) {
        int t = tid & 1, l = tid >> 1;
        float v = part[0 * 130 + t * 65 + l] + part[1 * 130 + t * 65 + l] +
                  part[2 * 130 + t * 65 + l] + part[3 * 130 + t * 65 + l];
        v += bias[tid];
        out[(size_t)n * 128 + tid] = v > 0.f ? v : (__expf(v) - 1.f);
    }
}

// ---------------- mean pool (block-reduced partials + one atomic/feature) -----
__global__ __launch_bounds__(256) void pool_sum_kernel(const float* __restrict__ o2,
                                                       float* __restrict__ pool, int N) {
    __shared__ float4 sred[256];
    int f4 = threadIdx.x & 31;                 // float4 group (features f4*4..+3)
    int r = blockIdx.x * 256 + (threadIdx.x >> 5);
    float4 acc = {0.f, 0.f, 0.f, 0.f};
    for (int i = 0; i < 32; i++, r += 8) {
        if (r < N) {
            float4 v = *(const float4*)&o2[(size_t)r * 128 + f4 * 4];
            acc.x += v.x; acc.y += v.y; acc.z += v.z; acc.w += v.w;
        }
    }
    sred[threadIdx.x] = acc;
    __syncthreads();
    if (threadIdx.x < 32) {
        float4 t = sred[threadIdx.x];
#pragma unroll
        for (int k = 1; k < 8; k++) {
            float4 u = sred[threadIdx.x + 32 * k];
            t.x += u.x; t.y += u.y; t.z += u.z; t.w += u.w;
        }
        atomicAdd(&pool[f4 * 4 + 0], t.x);
        atomicAdd(&pool[f4 * 4 + 1], t.y);
        atomicAdd(&pool[f4 * 4 + 2], t.z);
        atomicAdd(&pool[f4 * 4 + 3], t.w);
    }
}

__global__ __launch_bounds__(256) void final_out_kernel(const float* __restrict__ pool,
                                                        const float* __restrict__ Wout,
                                                        const float* __restrict__ bout,
                                                        float* __restrict__ out, float invN) {
    int o = threadIdx.x;
    float acc = 0.f;
    for (int k = 0; k < 128; k++) acc += pool[k] * Wout[k * 256 + o];
    out[o] = acc * invN + bout[o];
}

// ---------------- launch ------------------------------------------------------
extern "C" void kernel_launch(void* const* d_in, const int* in_sizes, int n_in,
                              void* d_out, int out_size, void* d_ws, size_t ws_size,
                              hipStream_t stream) {
    const float* x      = (const float*)d_in[0];
    const int*   ei     = (const int*)d_in[1];
    const float* W_emb  = (const float*)d_in[2];
    const float* b_emb  = (const float*)d_in[3];
    const float* W1     = (const float*)d_in[4];
    const float* a1_src = (const float*)d_in[5];
    const float* a1_dst = (const float*)d_in[6];
    const float* b1     = (const float*)d_in[7];
    const float* W2     = (const float*)d_in[8];
    const float* a2_src = (const float*)d_in[9];
    const float* a2_dst = (const float*)d_in[10];
    const float* b2     = (const float*)d_in[11];
    const float* W_out  = (const float*)d_in[12];
    const float* b_out  = (const float*)d_in[13];
    float* out = (float*)d_out;

    const int N = in_sizes[0] / 64;   // 25000
    const int E = in_sizes[1] / 2;    // 400000
    const int Etot = E + N;

    char* ws = (char*)d_ws;
    size_t off = 0;
    auto alloc = [&](size_t bytes) -> void* {
        void* p = ws + off;
        off = (off + bytes + 255) & ~(size_t)255;
        return p;
    };
    typedef unsigned short u16;
    u16* xb    = (u16*)alloc((size_t)N * 64 * 2);
    u16* WeT   = (u16*)alloc((size_t)128 * 64 * 2);
    u16* W1T   = (u16*)alloc((size_t)512 * 128 * 2);
    u16* W2T   = (u16*)alloc((size_t)128 * 512 * 2);
    u16* h0b   = (u16*)alloc((size_t)N * 128 * 2);
    u16* h1b   = (u16*)alloc((size_t)N * 512 * 2);
    u16* o1b   = (u16*)alloc((size_t)N * 512 * 2);
    u16* h2b   = (u16*)alloc((size_t)N * 128 * 2);
    float* o2  = (float*)alloc((size_t)N * 128 * 4);
    float* as1 = (float*)alloc((size_t)N * 4 * 4);
    float* ad1 = (float*)alloc((size_t)N * 4 * 4);
    float* as2 = (float*)alloc((size_t)N * 4);
    float* ad2 = (float*)alloc((size_t)N * 4);
    float* pool = (float*)alloc(128 * 4);
    int* rowptr = (int*)alloc((size_t)(N + 1) * 4);
    int* deg    = (int*)alloc((size_t)N * 4);
    int* cursor = (int*)alloc((size_t)N * 4);
    int* esrc   = (int*)alloc((size_t)Etot * 4);
    int* edst   = (int*)alloc((size_t)Etot * 4);
    float* eb1  = (float*)alloc((size_t)Etot * 4 * 4);
    float* eb2  = (float*)alloc((size_t)Etot * 4);

    hipMemsetAsync(deg, 0, (size_t)N * 4, stream);
    hipMemsetAsync(cursor, 0, (size_t)N * 4, stream);
    hipMemsetAsync(pool, 0, 128 * 4, stream);

    // CSR build
    int blocksE = (Etot + 255) / 256;
    deg_count_kernel<<<blocksE, 256, 0, stream>>>(ei, E, N, deg);
    csr_scan_kernel<<<1, 256, 0, stream>>>(deg, rowptr, N);
    scatter_kernel<<<blocksE, 256, 0, stream>>>(ei, E, N, rowptr, cursor, esrc, edst);

    // bf16 conversions / weight transposes
    conv_bf16_kernel<<<(N * 64 + 255) / 256, 256, 0, stream>>>(x, xb, N * 64);
    transpose_conv_kernel<<<(64 * 128 + 255) / 256, 256, 0, stream>>>(W_emb, WeT, 64, 128);
    transpose_conv_kernel<<<(128 * 512 + 255) / 256, 256, 0, stream>>>(W1, W1T, 128, 512);
    transpose_conv_kernel<<<(512 * 128 + 255) / 256, 256, 0, stream>>>(W2, W2T, 512, 128);

    int mtiles = (N + 127) / 128;
    gemm_mfma_nt<1><<<dim3(1, mtiles), 256, 0, stream>>>(xb, WeT, b_emb, h0b, N, 128, 64);
    gemm_mfma_nt<0><<<dim3(4, mtiles), 256, 0, stream>>>(h0b, W1T, nullptr, h1b, N, 512, 128);

    // layer-1 attention
    alpha_wave_kernel<4><<<(N * 64 + 255) / 256, 256, 0, stream>>>(h1b, a1_src, a1_dst, as1, ad1, N);
    edge_e1_kernel<<<blocksE, 256, 0, stream>>>(esrc, edst, (const float4*)as1, (const float4*)ad1,
                                                (float4*)eb1, Etot);
    gat_agg_l1<<<N, 256, 0, stream>>>(h1b, (const float4*)eb1, rowptr, esrc, b1, o1b);

    gemm_mfma_nt<0><<<dim3(1, mtiles), 256, 0, stream>>>(o1b, W2T, nullptr, h2b, N, 128, 512);

    // layer-2 attention
    alpha_wave_kernel<1><<<(N * 64 + 255) / 256, 256, 0, stream>>>(h2b, a2_src, a2_dst, as2, ad2, N);
    edge_e2_kernel<<<blocksE, 256, 0, stream>>>(esrc, edst, as2, ad2, eb2, Etot);
    gat_agg_l2<<<N, 256, 0, stream>>>(h2b, eb2, rowptr, esrc, b2, o2);

    // mean pool + final GEMV
    pool_sum_kernel<<<(N + 255) / 256, 256, 0, stream>>>(o2, pool, N);
    final_out_kernel<<<1, 256, 0, stream>>>(pool, W_out, b_out, out, 1.f / (float)N);
}

// Round 4
// 333.733 us; speedup vs baseline: 1.7973x; 1.3253x over previous
//
#include <hip/hip_runtime.h>
#include <hip/hip_bf16.h>

// N=25000, E=400000 (+N self loops), F_IN=64, HID=128, HEADS=4, OUT=256
// bf16 interior; aggregation = one WAVE per node (no barriers, readlane broadcast).

#define LRELU(x) ((x) > 0.f ? (x) : 0.2f * (x))

typedef short bf16x8 __attribute__((ext_vector_type(8)));
typedef float f32x4 __attribute__((ext_vector_type(4)));

static __device__ __forceinline__ unsigned short f2b(float f) {
    union { float f; unsigned u; } x; x.f = f;
    unsigned r = x.u + 0x7fff + ((x.u >> 16) & 1);
    return (unsigned short)(r >> 16);
}
static __device__ __forceinline__ float blo(unsigned u) {
    union { unsigned u; float f; } x; x.u = u << 16; return x.f;
}
static __device__ __forceinline__ float bhi(unsigned u) {
    union { unsigned u; float f; } x; x.u = u & 0xffff0000u; return x.f;
}
static __device__ __forceinline__ float rl_f(float v, int c) {
    return __int_as_float(__builtin_amdgcn_readlane(__float_as_int(v), c));
}

// ---------------- zero scratch (replaces 3 memsets) ---------------------------
__global__ void zero_kernel(int* __restrict__ deg, int* __restrict__ cursor,
                            float* __restrict__ pool, int N) {
    int i = blockIdx.x * blockDim.x + threadIdx.x;
    if (i < N) deg[i] = 0;
    else if (i < 2 * N) cursor[i - N] = 0;
    else if (i < 2 * N + 128) pool[i - 2 * N] = 0.f;
}

// ---------------- CSR build ----------------
__global__ void deg_count_kernel(const int* __restrict__ ei, int E, int N, int* __restrict__ deg) {
    int i = blockIdx.x * blockDim.x + threadIdx.x;
    if (i < E) atomicAdd(&deg[ei[E + i]], 1);
    else if (i < E + N) atomicAdd(&deg[i - E], 1);
}

// hierarchical exclusive scan of deg -> rowptr
__global__ __launch_bounds__(256) void scan_pass1(const int* __restrict__ deg, int* __restrict__ rowptr,
                                                  int* __restrict__ bsum, int N) {
    __shared__ int sd[256];
    int t = threadIdx.x, i = blockIdx.x * 256 + t;
    int d = (i < N) ? deg[i] : 0;
    sd[t] = d;
    __syncthreads();
    for (int off = 1; off < 256; off <<= 1) {
        int v = (t >= off) ? sd[t - off] : 0;
        __syncthreads();
        sd[t] += v;
        __syncthreads();
    }
    if (i < N) rowptr[i] = sd[t] - d;   // exclusive within block
    if (t == 255) bsum[blockIdx.x] = sd[t];
}

__global__ __launch_bounds__(128) void scan_pass2(const int* __restrict__ bsum, int* __restrict__ boff,
                                                  int* __restrict__ rowptr, int nb, int N) {
    __shared__ int sd[128];
    int t = threadIdx.x;
    int d = (t < nb) ? bsum[t] : 0;
    sd[t] = d;
    __syncthreads();
    for (int off = 1; off < 128; off <<= 1) {
        int v = (t >= off) ? sd[t - off] : 0;
        __syncthreads();
        sd[t] += v;
        __syncthreads();
    }
    if (t < nb) boff[t] = sd[t] - d;
    if (t == 127) rowptr[N] = sd[t];
}

__global__ __launch_bounds__(256) void scan_pass3(int* __restrict__ rowptr, const int* __restrict__ boff, int N) {
    int i = blockIdx.x * 256 + threadIdx.x;
    if (i < N) rowptr[i] += boff[blockIdx.x];
}

__global__ void scatter_kernel(const int* __restrict__ ei, int E, int N,
                               const int* __restrict__ rowptr, int* __restrict__ cursor,
                               int* __restrict__ esrc, int* __restrict__ edst) {
    int i = blockIdx.x * blockDim.x + threadIdx.x;
    int s, d;
    if (i < E) { s = ei[i]; d = ei[E + i]; }
    else if (i < E + N) { s = i - E; d = s; }
    else return;
    int pos = rowptr[d] + atomicAdd(&cursor[d], 1);
    esrc[pos] = s;
    edst[pos] = d;
}

// ---------------- per-edge logits (CSR order) ---------------------------------
__global__ void edge_e1_kernel(const int* __restrict__ esrc, const int* __restrict__ edst,
                               const float4* __restrict__ as4, const float4* __restrict__ ad4,
                               float4* __restrict__ eb, int Etot) {
    int i = blockIdx.x * blockDim.x + threadIdx.x;
    if (i >= Etot) return;
    float4 u = as4[esrc[i]];
    float4 v = ad4[edst[i]];
    float4 e;
    e.x = LRELU(u.x + v.x); e.y = LRELU(u.y + v.y);
    e.z = LRELU(u.z + v.z); e.w = LRELU(u.w + v.w);
    eb[i] = e;
}

__global__ void edge_e2_kernel(const int* __restrict__ esrc, const int* __restrict__ edst,
                               const float* __restrict__ as, const float* __restrict__ ad,
                               float* __restrict__ eb, int Etot) {
    int i = blockIdx.x * blockDim.x + threadIdx.x;
    if (i >= Etot) return;
    float e = as[esrc[i]] + ad[edst[i]];
    eb[i] = LRELU(e);
}

// ---------------- prep: x->bf16 + 3 weight transposes (one dispatch) ----------
__global__ void prep_kernel(const float* __restrict__ x, const float* __restrict__ We,
                            const float* __restrict__ W1, const float* __restrict__ W2,
                            unsigned short* __restrict__ xb, unsigned short* __restrict__ WeT,
                            unsigned short* __restrict__ W1T, unsigned short* __restrict__ W2T,
                            int Nx) {
    int i = blockIdx.x * blockDim.x + threadIdx.x;
    if (i < Nx) { xb[i] = f2b(x[i]); return; }
    i -= Nx;
    if (i < 64 * 128) { int k = i >> 7, n = i & 127; WeT[n * 64 + k] = f2b(We[i]); return; }
    i -= 64 * 128;
    if (i < 128 * 512) { int k = i >> 9, n = i & 511; W1T[n * 128 + k] = f2b(W1[i]); return; }
    i -= 128 * 512;
    if (i < 512 * 128) { int k = i >> 7, n = i & 127; W2T[n * 512 + k] = f2b(W2[i]); return; }
}

// ---------------- MFMA bf16 NT GEMM: C[M,N] = A[M,K] @ Bt[N,K]^T --------------
template <int ACT>
__global__ __launch_bounds__(256) void gemm_mfma_nt(const unsigned short* __restrict__ A,
                                                    const unsigned short* __restrict__ Bt,
                                                    const float* __restrict__ bias,
                                                    unsigned short* __restrict__ C,
                                                    int M, int N, int K) {
    __shared__ __align__(16) unsigned short As[128 * 40];
    __shared__ __align__(16) unsigned short Bs[128 * 40];
    int tid = threadIdx.x;
    int gm0 = blockIdx.y * 128, gn0 = blockIdx.x * 128;
    int w = tid >> 6, lane = tid & 63;
    int wrow = (w >> 1) * 64, wcol = (w & 1) * 64;
    int l15 = lane & 15, quad = lane >> 4;

    f32x4 acc[4][4];
#pragma unroll
    for (int i = 0; i < 4; i++)
#pragma unroll
        for (int j = 0; j < 4; j++) acc[i][j] = {0.f, 0.f, 0.f, 0.f};

    for (int k0 = 0; k0 < K; k0 += 32) {
#pragma unroll
        for (int rr = 0; rr < 2; rr++) {
            int lin = tid + rr * 256;
            int row = lin >> 2;
            int cg = (lin & 3) * 8;
            int grow = gm0 + row; if (grow >= M) grow = M - 1;
            uint4 va = *(const uint4*)&A[(size_t)grow * K + k0 + cg];
            *(uint4*)&As[row * 40 + cg] = va;
            uint4 vb = *(const uint4*)&Bt[(size_t)(gn0 + row) * K + k0 + cg];
            *(uint4*)&Bs[row * 40 + cg] = vb;
        }
        __syncthreads();
        bf16x8 af[4], bfr[4];
#pragma unroll
        for (int i = 0; i < 4; i++) {
            af[i]  = *(const bf16x8*)&As[(wrow + i * 16 + l15) * 40 + quad * 8];
            bfr[i] = *(const bf16x8*)&Bs[(wcol + i * 16 + l15) * 40 + quad * 8];
        }
#pragma unroll
        for (int i = 0; i < 4; i++)
#pragma unroll
            for (int j = 0; j < 4; j++)
                acc[i][j] = __builtin_amdgcn_mfma_f32_16x16x32_bf16(af[i], bfr[j], acc[i][j], 0, 0, 0);
        __syncthreads();
    }

#pragma unroll
    for (int i = 0; i < 4; i++) {
        int row = gm0 + wrow + i * 16 + quad * 4;
#pragma unroll
        for (int j = 0; j < 4; j++) {
            int col = gn0 + wcol + j * 16 + l15;
            float bv = bias ? bias[col] : 0.f;
#pragma unroll
            for (int r = 0; r < 4; r++) {
                int gr = row + r;
                if (gr < M) {
                    float v = acc[i][j][r] + bv;
                    if (ACT == 1) v = fmaxf(v, 0.f);
                    C[(size_t)gr * N + col] = f2b(v);
                }
            }
        }
    }
}

// ---------------- alpha: one wave per node, bf16 row, shuffle reduce ----------
template <int H>
__global__ __launch_bounds__(256) void alpha_wave_kernel(const unsigned short* __restrict__ hb,
                                                         const float* __restrict__ a_src,
                                                         const float* __restrict__ a_dst,
                                                         float* __restrict__ as_out,
                                                         float* __restrict__ ad_out, int N) {
    int wid = (blockIdx.x * 256 + threadIdx.x) >> 6;
    int lane = threadIdx.x & 63;
    if (wid >= N) return;
    const int F = H * 128;
    float ds = 0.f, dd = 0.f;
    if (lane * 8 < F) {
        uint4 v = *(const uint4*)&hb[(size_t)wid * F + lane * 8];
        unsigned uu[4] = {v.x, v.y, v.z, v.w};
#pragma unroll
        for (int t = 0; t < 4; t++) {
            float f0 = blo(uu[t]), f1 = bhi(uu[t]);
            int c = lane * 8 + 2 * t;
            ds += f0 * a_src[c] + f1 * a_src[c + 1];
            dd += f0 * a_dst[c] + f1 * a_dst[c + 1];
        }
    }
#pragma unroll
    for (int o = 1; o < 16; o <<= 1) {
        ds += __shfl_xor(ds, o);
        dd += __shfl_xor(dd, o);
    }
    if ((lane & 15) == 0) {
        int h = lane >> 4;
        if (h < H) {
            as_out[wid * H + h] = ds;
            ad_out[wid * H + h] = dd;
        }
    }
}

// ---------------- GAT agg L1 (H=4, C=512 out feats): one wave per node --------
__global__ __launch_bounds__(256) void gat_agg_l1(const unsigned short* __restrict__ hpre,
                                                  const float4* __restrict__ eb4,
                                                  const int* __restrict__ rowptr,
                                                  const int* __restrict__ esrc,
                                                  const float* __restrict__ bias,
                                                  unsigned short* __restrict__ out, int N) {
    __shared__ float wlds_all[4][256];
    int w = threadIdx.x >> 6, lane = threadIdx.x & 63;
    int n = blockIdx.x * 4 + w;
    if (n >= N) return;
    float* wlds = wlds_all[w];
    int begin = rowptr[n], end = rowptr[n + 1];
    int deg = end - begin;

    // pass 1: per-head max
    float4 m = {-3.4e38f, -3.4e38f, -3.4e38f, -3.4e38f};
    for (int base = 0; base < deg; base += 64) {
        int j = base + lane;
        if (j < deg) {
            float4 e = eb4[begin + j];
            m.x = fmaxf(m.x, e.x); m.y = fmaxf(m.y, e.y);
            m.z = fmaxf(m.z, e.z); m.w = fmaxf(m.w, e.w);
        }
    }
#pragma unroll
    for (int o = 32; o >= 1; o >>= 1) {
        m.x = fmaxf(m.x, __shfl_xor(m.x, o));
        m.y = fmaxf(m.y, __shfl_xor(m.y, o));
        m.z = fmaxf(m.z, __shfl_xor(m.z, o));
        m.w = fmaxf(m.w, __shfl_xor(m.w, o));
    }
    // pass 2: per-head sum of exp
    float4 s4 = {0.f, 0.f, 0.f, 0.f};
    for (int base = 0; base < deg; base += 64) {
        int j = base + lane;
        if (j < deg) {
            float4 e = eb4[begin + j];
            s4.x += __expf(e.x - m.x); s4.y += __expf(e.y - m.y);
            s4.z += __expf(e.z - m.z); s4.w += __expf(e.w - m.w);
        }
    }
#pragma unroll
    for (int o = 32; o >= 1; o >>= 1) {
        s4.x += __shfl_xor(s4.x, o); s4.y += __shfl_xor(s4.y, o);
        s4.z += __shfl_xor(s4.z, o); s4.w += __shfl_xor(s4.w, o);
    }
    float4 inv = {1.f / (s4.x + 1e-16f), 1.f / (s4.y + 1e-16f),
                  1.f / (s4.z + 1e-16f), 1.f / (s4.w + 1e-16f)};

    // pass 3: weighted gather; lane covers features lane*8..+7; head h = lane>>4
    float acc[8] = {};
    int h = lane >> 4;
    for (int base = 0; base < deg; base += 64) {
        int j = base + lane;
        int len = min(64, deg - base);
        int s_l = 0;
        if (j < deg) {
            s_l = esrc[begin + j];
            float4 e = eb4[begin + j];
            float4 wv;
            wv.x = __expf(e.x - m.x) * inv.x;
            wv.y = __expf(e.y - m.y) * inv.y;
            wv.z = __expf(e.z - m.z) * inv.z;
            wv.w = __expf(e.w - m.w) * inv.w;
            *(float4*)&wlds[lane * 4] = wv;   // wave-private region: no barrier needed
        }
        int c = 0;
        for (; c + 2 <= len; c += 2) {
            int s0 = __builtin_amdgcn_readlane(s_l, c);
            int s1 = __builtin_amdgcn_readlane(s_l, c + 1);
            uint4 h0 = *((const uint4*)(hpre + ((size_t)s0 << 9)) + lane);
            uint4 h1 = *((const uint4*)(hpre + ((size_t)s1 << 9)) + lane);
            float w0 = wlds[c * 4 + h];
            float w1 = wlds[c * 4 + 4 + h];
            acc[0] += w0 * blo(h0.x); acc[1] += w0 * bhi(h0.x);
            acc[2] += w0 * blo(h0.y); acc[3] += w0 * bhi(h0.y);
            acc[4] += w0 * blo(h0.z); acc[5] += w0 * bhi(h0.z);
            acc[6] += w0 * blo(h0.w); acc[7] += w0 * bhi(h0.w);
            acc[0] += w1 * blo(h1.x); acc[1] += w1 * bhi(h1.x);
            acc[2] += w1 * blo(h1.y); acc[3] += w1 * bhi(h1.y);
            acc[4] += w1 * blo(h1.z); acc[5] += w1 * bhi(h1.z);
            acc[6] += w1 * blo(h1.w); acc[7] += w1 * bhi(h1.w);
        }
        if (c < len) {
            int s0 = __builtin_amdgcn_readlane(s_l, c);
            uint4 h0 = *((const uint4*)(hpre + ((size_t)s0 << 9)) + lane);
            float w0 = wlds[c * 4 + h];
            acc[0] += w0 * blo(h0.x); acc[1] += w0 * bhi(h0.x);
            acc[2] += w0 * blo(h0.y); acc[3] += w0 * bhi(h0.y);
            acc[4] += w0 * blo(h0.z); acc[5] += w0 * bhi(h0.z);
            acc[6] += w0 * blo(h0.w); acc[7] += w0 * bhi(h0.w);
        }
    }
    // epilogue: bias + ELU + pack bf16x8 -> one 16B store
    int f0 = lane * 8;
    unsigned pk[4];
#pragma unroll
    for (int k = 0; k < 4; k++) {
        float v0 = acc[2 * k] + bias[f0 + 2 * k];
        float v1 = acc[2 * k + 1] + bias[f0 + 2 * k + 1];
        v0 = v0 > 0.f ? v0 : (__expf(v0) - 1.f);
        v1 = v1 > 0.f ? v1 : (__expf(v1) - 1.f);
        pk[k] = (unsigned)f2b(v0) | ((unsigned)f2b(v1) << 16);
    }
    uint4 pv = {pk[0], pk[1], pk[2], pk[3]};
    *((uint4*)(out + (size_t)n * 512) + lane) = pv;
}

// ---------------- GAT agg L2 (H=1, C=128): one wave per node ------------------
__global__ __launch_bounds__(256) void gat_agg_l2(const unsigned short* __restrict__ hpre,
                                                  const float* __restrict__ eb,
                                                  const int* __restrict__ rowptr,
                                                  const int* __restrict__ esrc,
                                                  const float* __restrict__ bias,
                                                  float* __restrict__ out, int N) {
    int w = threadIdx.x >> 6, lane = threadIdx.x & 63;
    int n = blockIdx.x * 4 + w;
    if (n >= N) return;
    int begin = rowptr[n], end = rowptr[n + 1];
    int deg = end - begin;

    float m = -3.4e38f;
    for (int base = 0; base < deg; base += 64) {
        int j = base + lane;
        if (j < deg) m = fmaxf(m, eb[begin + j]);
    }
#pragma unroll
    for (int o = 32; o >= 1; o >>= 1) m = fmaxf(m, __shfl_xor(m, o));

    float s = 0.f;
    for (int base = 0; base < deg; base += 64) {
        int j = base + lane;
        if (j < deg) s += __expf(eb[begin + j] - m);
    }
#pragma unroll
    for (int o = 32; o >= 1; o >>= 1) s += __shfl_xor(s, o);
    float inv = 1.f / (s + 1e-16f);

    float acc0 = 0.f, acc1 = 0.f;
    for (int base = 0; base < deg; base += 64) {
        int j = base + lane;
        int len = min(64, deg - base);
        int s_l = 0; float w_l = 0.f;
        if (j < deg) {
            s_l = esrc[begin + j];
            w_l = __expf(eb[begin + j] - m) * inv;
        }
        int c = 0;
        for (; c + 2 <= len; c += 2) {
            int sp0 = __builtin_amdgcn_readlane(s_l, c);
            int sp1 = __builtin_amdgcn_readlane(s_l, c + 1);
            float w0 = rl_f(w_l, c), w1 = rl_f(w_l, c + 1);
            unsigned u0 = *((const unsigned*)(hpre + ((size_t)sp0 << 7)) + lane);
            unsigned u1 = *((const unsigned*)(hpre + ((size_t)sp1 << 7)) + lane);
            acc0 += w0 * blo(u0); acc1 += w0 * bhi(u0);
            acc0 += w1 * blo(u1); acc1 += w1 * bhi(u1);
        }
        if (c < len) {
            int sp0 = __builtin_amdgcn_readlane(s_l, c);
            float w0 = rl_f(w_l, c);
            unsigned u0 = *((const unsigned*)(hpre + ((size_t)sp0 << 7)) + lane);
            acc0 += w0 * blo(u0); acc1 += w0 * bhi(u0);
        }
    }
    float v0 = acc0 + bias[lane * 2];
    float v1 = acc1 + bias[lane * 2 + 1];
    v0 = v0 > 0.f ? v0 : (__expf(v0) - 1.f);
    v1 = v1 > 0.f ? v1 : (__expf(v1) - 1.f);
    float2 pv = {v0, v1};
    *(float2*)&out[(size_t)n * 128 + lane * 2] = pv;
}

// ---------------- mean pool + final GEMV --------------------------------------
__global__ __launch_bounds__(256) void pool_sum_kernel(const float* __restrict__ o2,
                                                       float* __restrict__ pool, int N) {
    __shared__ float4 sred[256];
    int f4 = threadIdx.x & 31;
    int r = blockIdx.x * 256 + (threadIdx.x >> 5);
    float4 acc = {0.f, 0.f, 0.f, 0.f};
    for (int i = 0; i < 32; i++, r += 8) {
        if (r < N) {
            float4 v = *(const float4*)&o2[(size_t)r * 128 + f4 * 4];
            acc.x += v.x; acc.y += v.y; acc.z += v.z; acc.w += v.w;
        }
    }
    sred[threadIdx.x] = acc;
    __syncthreads();
    if (threadIdx.x < 32) {
        float4 t = sred[threadIdx.x];
#pragma unroll
        for (int k = 1; k < 8; k++) {
            float4 u = sred[threadIdx.x + 32 * k];
            t.x += u.x; t.y += u.y; t.z += u.z; t.w += u.w;
        }
        atomicAdd(&pool[f4 * 4 + 0], t.x);
        atomicAdd(&pool[f4 * 4 + 1], t.y);
        atomicAdd(&pool[f4 * 4 + 2], t.z);
        atomicAdd(&pool[f4 * 4 + 3], t.w);
    }
}

__global__ __launch_bounds__(256) void final_out_kernel(const float* __restrict__ pool,
                                                        const float* __restrict__ Wout,
                                                        const float* __restrict__ bout,
                                                        float* __restrict__ out, float invN) {
    int o = threadIdx.x;
    float acc = 0.f;
    for (int k = 0; k < 128; k++) acc += pool[k] * Wout[k * 256 + o];
    out[o] = acc * invN + bout[o];
}

// ---------------- launch ------------------------------------------------------
extern "C" void kernel_launch(void* const* d_in, const int* in_sizes, int n_in,
                              void* d_out, int out_size, void* d_ws, size_t ws_size,
                              hipStream_t stream) {
    const float* x      = (const float*)d_in[0];
    const int*   ei     = (const int*)d_in[1];
    const float* W_emb  = (const float*)d_in[2];
    const float* b_emb  = (const float*)d_in[3];
    const float* W1     = (const float*)d_in[4];
    const float* a1_src = (const float*)d_in[5];
    const float* a1_dst = (const float*)d_in[6];
    const float* b1     = (const float*)d_in[7];
    const float* W2     = (const float*)d_in[8];
    const float* a2_src = (const float*)d_in[9];
    const float* a2_dst = (const float*)d_in[10];
    const float* b2     = (const float*)d_in[11];
    const float* W_out  = (const float*)d_in[12];
    const float* b_out  = (const float*)d_in[13];
    float* out = (float*)d_out;

    const int N = in_sizes[0] / 64;   // 25000
    const int E = in_sizes[1] / 2;    // 400000
    const int Etot = E + N;
    const int nb = (N + 255) / 256;   // scan blocks (must be <= 128)

    char* ws = (char*)d_ws;
    size_t off = 0;
    auto alloc = [&](size_t bytes) -> void* {
        void* p = ws + off;
        off = (off + bytes + 255) & ~(size_t)255;
        return p;
    };
    typedef unsigned short u16;
    u16* xb    = (u16*)alloc((size_t)N * 64 * 2);
    u16* WeT   = (u16*)alloc((size_t)128 * 64 * 2);
    u16* W1T   = (u16*)alloc((size_t)512 * 128 * 2);
    u16* W2T   = (u16*)alloc((size_t)128 * 512 * 2);
    u16* h0b   = (u16*)alloc((size_t)N * 128 * 2);
    u16* h1b   = (u16*)alloc((size_t)N * 512 * 2);
    u16* o1b   = (u16*)alloc((size_t)N * 512 * 2);
    u16* h2b   = (u16*)alloc((size_t)N * 128 * 2);
    float* o2  = (float*)alloc((size_t)N * 128 * 4);
    float* as1 = (float*)alloc((size_t)N * 4 * 4);
    float* ad1 = (float*)alloc((size_t)N * 4 * 4);
    float* as2 = (float*)alloc((size_t)N * 4);
    float* ad2 = (float*)alloc((size_t)N * 4);
    float* pool = (float*)alloc(128 * 4);
    int* rowptr = (int*)alloc((size_t)(N + 1) * 4);
    int* deg    = (int*)alloc((size_t)N * 4);
    int* cursor = (int*)alloc((size_t)N * 4);
    int* bsum   = (int*)alloc(128 * 4);
    int* boff   = (int*)alloc(128 * 4);
    int* esrc   = (int*)alloc((size_t)Etot * 4);
    int* edst   = (int*)alloc((size_t)Etot * 4);
    float* eb1  = (float*)alloc((size_t)Etot * 4 * 4);
    float* eb2  = (float*)alloc((size_t)Etot * 4);

    // zero scratch
    zero_kernel<<<(2 * N + 128 + 255) / 256, 256, 0, stream>>>(deg, cursor, pool, N);

    // CSR build
    int blocksE = (Etot + 255) / 256;
    deg_count_kernel<<<blocksE, 256, 0, stream>>>(ei, E, N, deg);
    scan_pass1<<<nb, 256, 0, stream>>>(deg, rowptr, bsum, N);
    scan_pass2<<<1, 128, 0, stream>>>(bsum, boff, rowptr, nb, N);
    scan_pass3<<<nb, 256, 0, stream>>>(rowptr, boff, N);
    scatter_kernel<<<blocksE, 256, 0, stream>>>(ei, E, N, rowptr, cursor, esrc, edst);

    // bf16 conversions + weight transposes (single dispatch)
    int Nx = N * 64;
    int prep_elems = Nx + 64 * 128 + 128 * 512 + 512 * 128;
    prep_kernel<<<(prep_elems + 255) / 256, 256, 0, stream>>>(x, W_emb, W1, W2, xb, WeT, W1T, W2T, Nx);

    int mtiles = (N + 127) / 128;
    gemm_mfma_nt<1><<<dim3(1, mtiles), 256, 0, stream>>>(xb, WeT, b_emb, h0b, N, 128, 64);
    gemm_mfma_nt<0><<<dim3(4, mtiles), 256, 0, stream>>>(h0b, W1T, nullptr, h1b, N, 512, 128);

    // layer-1 attention + aggregation
    alpha_wave_kernel<4><<<(N * 64 + 255) / 256, 256, 0, stream>>>(h1b, a1_src, a1_dst, as1, ad1, N);
    edge_e1_kernel<<<blocksE, 256, 0, stream>>>(esrc, edst, (const float4*)as1, (const float4*)ad1,
                                                (float4*)eb1, Etot);
    gat_agg_l1<<<(N + 3) / 4, 256, 0, stream>>>(h1b, (const float4*)eb1, rowptr, esrc, b1, o1b, N);

    gemm_mfma_nt<0><<<dim3(1, mtiles), 256, 0, stream>>>(o1b, W2T, nullptr, h2b, N, 128, 512);

    // layer-2 attention + aggregation
    alpha_wave_kernel<1><<<(N * 64 + 255) / 256, 256, 0, stream>>>(h2b, a2_src, a2_dst, as2, ad2, N);
    edge_e2_kernel<<<blocksE, 256, 0, stream>>>(esrc, edst, as2, ad2, eb2, Etot);
    gat_agg_l2<<<(N + 3) / 4, 256, 0, stream>>>(h2b, eb2, rowptr, esrc, b2, o2, N);

    // mean pool + final GEMV
    pool_sum_kernel<<<(N + 255) / 256, 256, 0, stream>>>(o2, pool, N);
    final_out_kernel<<<1, 256, 0, stream>>>(pool, W_out, b_out, out, 1.f / (float)N);
}